// Round 12
// baseline (73.281 us; speedup 1.0000x reference)
//
#include <hip/hip_runtime.h>

#define DIMD 512
#define NB 2
#define SEQ 2048
#define NHEADS 8
#define HDIM 64
#define MROWS (NB*SEQ)   // 4096

typedef short s16x8 __attribute__((ext_vector_type(8)));
typedef float f32x4 __attribute__((ext_vector_type(4)));
typedef float f32x16 __attribute__((ext_vector_type(16)));
typedef unsigned short u16;
typedef unsigned int u32;

__device__ __forceinline__ u16 f2bf(float f) {
    union { float f; u32 u; } c; c.f = f;
    u32 u = c.u;
    return (u16)((u + 0x7FFFu + ((u >> 16) & 1u)) >> 16);
}
__device__ __forceinline__ float bf2f(u16 v) {
    union { u32 u; float f; } c; c.u = ((u32)v) << 16;
    return c.f;
}

__device__ __forceinline__ f32x4 mfma16(s16x8 a, s16x8 b, f32x4 c) {
    return __builtin_amdgcn_mfma_f32_16x16x32_bf16(a, b, c, 0, 0, 0);
}
__device__ __forceinline__ f32x16 mfma32(s16x8 a, s16x8 b, f32x16 c) {
    return __builtin_amdgcn_mfma_f32_32x32x16_bf16(a, b, c, 0, 0, 0);
}
// Raw v_exp_f32: exact for |x| << 126 (scores are O(5)); 1 TRANS instr vs libm's ~6 VALU.
__device__ __forceinline__ float fexp2(float x) {
    float r; asm("v_exp_f32 %0, %1" : "=v"(r) : "v"(x)); return r;
}
__device__ __forceinline__ float frcp(float x) {
    float r; asm("v_rcp_f32 %0, %1" : "=v"(r) : "v"(x)); return r;
}

#define GLDS16(g, l) __builtin_amdgcn_global_load_lds( \
    (const __attribute__((address_space(1))) void*)(g), \
    (__attribute__((address_space(3))) void*)(l), 16, 0, 0)

#define ESCF 0.180336880111f   // 0.125 * log2(e), folded into Q at GEMM epilogue
#define HSC2 0.115524530f      // (0.125/6) / ESCF

// ---------------- fp32 -> bf16 convert: x + all four weights, one launch ----------------
__global__ void cvt_all(const float* __restrict__ x, const float* __restrict__ Wq,
                        const float* __restrict__ Wk, const float* __restrict__ Wv,
                        const float* __restrict__ Wo,
                        u16* __restrict__ xb, u16* __restrict__ wqkv, u16* __restrict__ wo) {
    int i = blockIdx.x * blockDim.x + threadIdx.x;   // 0..786431
    const float* src; u16* dst; int idx;
    if (i < 524288) { src = x; dst = xb; idx = i; }
    else {
        int jj = i - 524288;
        int which = jj >> 16; idx = jj & 65535;
        src = which == 0 ? Wq : which == 1 ? Wk : which == 2 ? Wv : Wo;
        dst = which < 3 ? wqkv + which*DIMD*DIMD : wo;
    }
    float4 v = reinterpret_cast<const float4*>(src)[idx];
    ushort4 o;
    o.x = f2bf(v.x); o.y = f2bf(v.y); o.z = f2bf(v.z); o.w = f2bf(v.w);
    reinterpret_cast<ushort4*>(dst)[idx] = o;
}

// ---------------- 128x64 GEMM: C = A[M,K] @ B[N,K]^T, 3 blocks/CU at this shape ----------------
// WMODE 3: QKV merged, N=1536; region0 q (pre-scaled ESCF), region1 k, region2 vt[b][h][d][s].
template<int WMODE>
__global__ __launch_bounds__(256) void gemm128x64(const u16* __restrict__ A, const u16* __restrict__ Bm,
                                                  void* __restrict__ Cout, void* __restrict__ Cout2,
                                                  void* __restrict__ Cout3, int M, int N, int K) {
    __shared__ u16 As[128*64];
    __shared__ u16 Bs[64*64];
    const int bm0 = blockIdx.x * 128, bn0 = blockIdx.y * 64;
    const int t = threadIdx.x;
    const int w = t >> 6, l = t & 63;
    const int lg = l >> 4, lr = l & 15;
    f32x4 acc[2][4] = {};
    const int sr8 = l >> 3;
    const int swc = ((l & 7) ^ (sr8 & 7)) * 8;
    const int arow = w*32 + sr8;                 // A: wave w stages rows w*32 + g*8 + sr8
    const int brow = w*8 + sr8;                  // B: stages rows g*32 + w*8 + sr8
    const u16* asrc = A  + (size_t)(bm0 + arow)*K + swc;
    const u16* bsrc = Bm + (size_t)(bn0 + brow)*K + swc;

    for (int k0 = 0; k0 < K; k0 += 64) {
        #pragma unroll
        for (int g = 0; g < 4; g++)
            GLDS16(asrc + (size_t)g*8*K + k0, &As[w*2048 + g*512]);
        #pragma unroll
        for (int g = 0; g < 2; g++)
            GLDS16(bsrc + (size_t)g*32*K + k0, &Bs[g*2048 + w*512]);
        __syncthreads();
        #pragma unroll
        for (int ks = 0; ks < 2; ks++) {
            const int swr = ((ks*4 + lg) ^ (lr & 7)) * 8;
            s16x8 af[2], bfr[4];
            #pragma unroll
            for (int fm = 0; fm < 2; fm++)
                af[fm] = *(const s16x8*)&As[(w*32 + fm*16 + lr)*64 + swr];
            #pragma unroll
            for (int fn = 0; fn < 4; fn++)
                bfr[fn] = *(const s16x8*)&Bs[(fn*16 + lr)*64 + swr];
            #pragma unroll
            for (int fm = 0; fm < 2; fm++)
                #pragma unroll
                for (int fn = 0; fn < 4; fn++)
                    acc[fm][fn] = mfma16(af[fm], bfr[fn], acc[fm][fn]);
        }
        __syncthreads();
    }

    const int region = (WMODE == 3) ? (bn0 >> 9) : 0;
    const float qsc = (WMODE == 3 && region == 0) ? ESCF : 1.0f;
    #pragma unroll
    for (int fm = 0; fm < 2; fm++) {
        #pragma unroll
        for (int fn = 0; fn < 4; fn++) {
            const int mb = bm0 + w*32 + fm*16 + lg*4;
            const int n  = bn0 + fn*16 + lr;
            if (WMODE == 2) {
                float* C = (float*)Cout;
                #pragma unroll
                for (int i = 0; i < 4; i++)
                    C[(size_t)(mb + i)*N + n] = acc[fm][fn][i];
            } else {
                const int nl = n & 511;
                if (region == 2) {
                    const int b = mb >> 11, s0 = mb & 2047;
                    const int h = nl >> 6, d = nl & 63;
                    ushort4 pk;
                    pk.x = f2bf(acc[fm][fn][0]);
                    pk.y = f2bf(acc[fm][fn][1]);
                    pk.z = f2bf(acc[fm][fn][2]);
                    pk.w = f2bf(acc[fm][fn][3]);
                    *(ushort4*)((u16*)Cout3 + (size_t)((b*8 + h)*64 + d)*2048 + s0) = pk;
                } else {
                    u16* C = region == 0 ? (u16*)Cout : (u16*)Cout2;
                    #pragma unroll
                    for (int i = 0; i < 4; i++)
                        C[(size_t)(mb + i)*512 + nl] = f2bf(acc[fm][fn][i] * qsc);
                }
            }
        }
    }
}

// ---------------- fused: combine NS split-K partials + normalize + Wo GEMM (32x64 tile) ----------------
template<int NS>
__global__ __launch_bounds__(256) void gemm_bt2f(const u16* __restrict__ opart,
                                                 const float* __restrict__ gpart,
                                                 const u16* __restrict__ Bm,
                                                 u16* __restrict__ Cout) {
    __shared__ u16 As[32*64];
    __shared__ u16 Bs[64*64];
    __shared__ float ginv[32][9];   // +1 pad: spread banks
    const int bm0 = blockIdx.x * 32, bn0 = blockIdx.y * 64;
    const int t = threadIdx.x;
    const int w = t >> 6, l = t & 63;
    const int lg = l >> 4, lr = l & 15;
    const int wm = w >> 1, wn = w & 1;
    f32x4 acc[2] = {};
    const int srow = t >> 3;            // 0..31
    const int c8 = t & 7;
    const int scol = c8 * 8;
    const int swz = (c8 ^ (srow & 7)) * 8;   // swizzled chunk (write pos for A, src col for B)

    // precompute 1/denominator for the 32 rows x 8 heads this block touches (256 = 1/thread)
    {
        const int r = t >> 3, h = t & 7;
        const int rg = bm0 + r;
        const int b = rg >> 11, s = rg & 2047;
        float g = 0.f;
        #pragma unroll
        for (int p = 0; p < NS; p++)
            g += gpart[(size_t)(p*16 + b*8 + h)*SEQ + s];
        ginv[r][h] = frcp(g);
    }
    __syncthreads();

    for (int k0 = 0; k0 < DIMD; k0 += 64) {
        const int h = k0 >> 6;          // head of this k-slab (cols k0..k0+63)
        // B: async staged, source pre-swizzled -> linear LDS holds col p^(row&7) at pos p
        #pragma unroll
        for (int c = 0; c < 2; c++) {
            const u16* gb = Bm + (size_t)(bn0 + c*32 + srow)*DIMD + k0 + swz;
            GLDS16(gb, (char*)Bs + c*4096 + w*1024);
        }
        // A: reg-staged fused normalize of NS partials (32 rows, 1 chunk/thread)
        {
            const int rl = srow;
            const int rg = bm0 + rl;
            const u16* oprow = opart + (size_t)rg*DIMD + k0 + scol;
            s16x8 pv[NS];
            #pragma unroll
            for (int p = 0; p < NS; p++)
                pv[p] = *(const s16x8*)(oprow + (size_t)p*MROWS*DIMD);
            const float inv = ginv[rl][h];
            union { u32 uu[4]; s16x8 v; } av;
            #pragma unroll
            for (int e2 = 0; e2 < 4; e2++) {
                float s0 = 0.f, s1 = 0.f;
                #pragma unroll
                for (int p = 0; p < NS; p++) {
                    s0 += bf2f((u16)pv[p][2*e2]);
                    s1 += bf2f((u16)pv[p][2*e2+1]);
                }
                asm("v_cvt_pk_bf16_f32 %0, %1, %2" : "=v"(av.uu[e2]) : "v"(s0*inv), "v"(s1*inv));
            }
            *(s16x8*)&As[rl*64 + swz] = av.v;
        }
        __syncthreads();
        #pragma unroll
        for (int ks = 0; ks < 2; ks++) {
            const int rc = ((ks*4 + lg) ^ (lr & 7)) * 8;
            s16x8 af = *(const s16x8*)&As[(wm*16 + lr)*64 + rc];
            s16x8 bfr[2];
            #pragma unroll
            for (int fn = 0; fn < 2; fn++)
                bfr[fn] = *(const s16x8*)&Bs[(wn*32 + fn*16 + lr)*64 + rc];
            #pragma unroll
            for (int fn = 0; fn < 2; fn++)
                acc[fn] = mfma16(af, bfr[fn], acc[fn]);
        }
        __syncthreads();
    }

    #pragma unroll
    for (int fn = 0; fn < 2; fn++) {
        const int mb = bm0 + wm*16 + lg*4;
        const int n  = bn0 + wn*32 + fn*16 + lr;
        #pragma unroll
        for (int i = 0; i < 4; i++)
            Cout[(size_t)(mb + i)*DIMD + n] = f2bf(acc[fn][i]);
    }
}

// ---------------- fused flash attention, split-K(4), cross-tile pipelined (r7-best, fallback) ----------------
__global__ __launch_bounds__(256) void attn_split(const u16* __restrict__ q, const u16* __restrict__ k,
                                                  const u16* __restrict__ vt,
                                                  u16* __restrict__ opart, float* __restrict__ gpart) {
    __shared__ u16 Ks[3][64*64];
    __shared__ u16 Vs[2][64*64];
    const int bid = blockIdx.x;
    const int xcd = bid & 7, j = bid >> 3;      // j: 0..127
    const int g8 = j >> 4, qt = j & 15;         // 8 (bh,ks) groups per XCD, 16 q-tiles each
    const int bhks = xcd*8 + g8;                // 0..63
    const int bh = bhks >> 2, ks = bhks & 3;
    const int b = bh >> 3, h = bh & 7;
    const int qb0 = qt * 128;
    const int t = threadIdx.x;
    const int w = t >> 6, l = t & 63;
    const int ln = l & 31, hi = l >> 5, l7 = l & 7;

    const size_t qrow = (size_t)(b*SEQ + qb0 + w*32 + ln);
    s16x8 qf[4];
    #pragma unroll
    for (int c = 0; c < 4; c++)
        qf[c] = *(const s16x8*)(q + qrow*DIMD + h*HDIM + c*16 + hi*8);

    const int sr = l >> 3;
    const int swc = ((l & 7) ^ sr) * 8;
    const u16* ksrc = k  + (size_t)(b*SEQ + ks*512 + w*16 + sr)*DIMD + h*HDIM + swc;
    const u16* vsrc = vt + (size_t)bh*HDIM*SEQ + (size_t)(w*16 + sr)*SEQ + ks*512 + swc;
    const int ldsw = w*1024;

    f32x16 o0 = {}, o1 = {};
    float gacc = 0.f;

#define SV(T, B) do { GLDS16(vsrc + (T)*64,                 &Vs[B][ldsw]); \
                      GLDS16(vsrc + (size_t)8*SEQ + (T)*64, &Vs[B][ldsw + 512]); } while(0)
#define SK(T, B) do { GLDS16(ksrc + (size_t)((T)*64)*DIMD,     &Ks[B][ldsw]); \
                      GLDS16(ksrc + (size_t)((T)*64 + 8)*DIMD, &Ks[B][ldsw + 512]); } while(0)
#define WB(N) do { asm volatile("s_waitcnt vmcnt(" #N ")" ::: "memory"); \
                   __builtin_amdgcn_s_barrier(); \
                   asm volatile("" ::: "memory"); } while(0)
#define QKH(B, KB, SC) do { SC = (f32x16){}; \
    __builtin_amdgcn_s_setprio(1); \
    _Pragma("unroll") for (int c_ = 0; c_ < 4; c_++) { \
        const int ch_ = (((c_ << 1) | hi) ^ l7) * 8; \
        s16x8 kf_ = *(const s16x8*)&Ks[B][((KB)*32 + ln)*64 + ch_]; \
        SC = mfma32(kf_, qf[c_], SC); } \
    __builtin_amdgcn_s_setprio(0); } while(0)
#define SMPV(SC, KB, VB) do { \
    u32 up_[4][2]; \
    _Pragma("unroll") for (int b2_ = 0; b2_ < 4; b2_++) { \
        const float s0_ = SC[b2_*4+0], s1_ = SC[b2_*4+1]; \
        const float s2_ = SC[b2_*4+2], s3_ = SC[b2_*4+3]; \
        const float w0_ = fexp2(s0_) * __builtin_amdgcn_fmed3f(s0_*HSC2 + 0.5f, 0.f, 1.f); \
        const float w1_ = fexp2(s1_) * __builtin_amdgcn_fmed3f(s1_*HSC2 + 0.5f, 0.f, 1.f); \
        const float w2_ = fexp2(s2_) * __builtin_amdgcn_fmed3f(s2_*HSC2 + 0.5f, 0.f, 1.f); \
        const float w3_ = fexp2(s3_) * __builtin_amdgcn_fmed3f(s3_*HSC2 + 0.5f, 0.f, 1.f); \
        gacc += (w0_ + w1_) + (w2_ + w3_); \
        asm("v_cvt_pk_bf16_f32 %0, %1, %2" : "=v"(up_[b2_][0]) : "v"(w0_), "v"(w1_)); \
        asm("v_cvt_pk_bf16_f32 %0, %1, %2" : "=v"(up_[b2_][1]) : "v"(w2_), "v"(w3_)); } \
    _Pragma("unroll") for (int c16_ = 0; c16_ < 2; c16_++) { \
        u32 x0_ = up_[2*c16_][0], y0_ = up_[2*c16_+1][0]; \
        u32 x1_ = up_[2*c16_][1], y1_ = up_[2*c16_+1][1]; \
        asm("v_permlane32_swap_b32 %0, %1" : "+v"(x0_), "+v"(y0_)); \
        asm("v_permlane32_swap_b32 %0, %1" : "+v"(x1_), "+v"(y1_)); \
        union { u32 w[4]; s16x8 v; } pa_; \
        pa_.w[0] = x0_; pa_.w[1] = x1_; pa_.w[2] = y0_; pa_.w[3] = y1_; \
        const int ccv_ = (KB)*4 + c16_*2 + hi; \
        s16x8 vf0_ = *(const s16x8*)&Vs[VB][(size_t)ln*64        + (ccv_ ^ l7)*8]; \
        s16x8 vf1_ = *(const s16x8*)&Vs[VB][(size_t)(32 + ln)*64 + (ccv_ ^ l7)*8]; \
        __builtin_amdgcn_s_setprio(1); \
        o0 = mfma32(pa_.v, vf0_, o0); \
        o1 = mfma32(pa_.v, vf1_, o1); \
        __builtin_amdgcn_s_setprio(0); } } while(0)

    f32x16 a0, a1, b0, b1;
    SV(0,0); SK(0,0); SK(1,1);
    WB(2);
    QKH(0,0,a0); SK(2,2); QKH(0,1,a1);
    WB(2);
    SV(1,1); QKH(1,0,b0); SK(3,0); SMPV(a0,0,0); QKH(1,1,b1); SMPV(a1,1,0);
    WB(2);
    SV(2,0); QKH(2,0,a0); SK(4,1); SMPV(b0,0,1); QKH(2,1,a1); SMPV(b1,1,1);
    WB(2);
    SV(3,1); QKH(0,0,b0); SK(5,2); SMPV(a0,0,0); QKH(0,1,b1); SMPV(a1,1,0);
    WB(2);
    SV(4,0); QKH(1,0,a0); SK(6,0); SMPV(b0,0,1); QKH(1,1,a1); SMPV(b1,1,1);
    WB(2);
    SV(5,1); QKH(2,0,b0); SK(7,1); SMPV(a0,0,0); QKH(2,1,b1); SMPV(a1,1,0);
    WB(2);
    SV(6,0); QKH(0,0,a0); SMPV(b0,0,1); QKH(0,1,a1); SMPV(b1,1,1);
    WB(0);
    SV(7,1); QKH(1,0,b0); SMPV(a0,0,0); QKH(1,1,b1); SMPV(a1,1,0);
    WB(0);
    SMPV(b0,0,1); SMPV(b1,1,1);

#undef SV
#undef SK
#undef WB
#undef QKH
#undef SMPV

    gacc += __shfl_xor(gacc, 32);
    if (l < 32)
        gpart[((size_t)ks*16 + bh)*SEQ + qb0 + w*32 + l] = gacc;

    u16* op = opart + ((size_t)ks*MROWS + b*SEQ + qb0 + w*32)*DIMD + h*HDIM;
    #pragma unroll
    for (int i = 0; i < 16; i++) {
        const int qr = (i & 3) + 8*(i >> 2) + 4*hi;
        op[(size_t)qr*DIMD + ln]      = f2bf(o0[i]);
        op[(size_t)qr*DIMD + 32 + ln] = f2bf(o1[i]);
    }
}

// ---------------- attention phase: 64 keys via 32x32x16 MFMA, P in-register ----------------
__device__ __forceinline__ void attn_phase64(const u16* Kc, const u16* Vc, const s16x8* qf,
                                             f32x16& o0, f32x16& o1, float& gacc,
                                             int ln, int hi, int l7) {
    f32x16 sc0 = {}, sc1 = {};
    __builtin_amdgcn_s_setprio(1);
    #pragma unroll
    for (int c = 0; c < 4; c++) {
        const int ch = (((c << 1) | hi) ^ l7) * 8;
        s16x8 kf0 = *(const s16x8*)&Kc[ln*64 + ch];
        s16x8 kf1 = *(const s16x8*)&Kc[(32 + ln)*64 + ch];
        sc0 = mfma32(kf0, qf[c], sc0);
        sc1 = mfma32(kf1, qf[c], sc1);
    }
    __builtin_amdgcn_s_setprio(0);
    #pragma unroll
    for (int kb = 0; kb < 2; kb++) {
        const f32x16& sc = kb ? sc1 : sc0;
        u32 u[4][2];
        #pragma unroll
        for (int b2 = 0; b2 < 4; b2++) {
            float ww[4];
            #pragma unroll
            for (int r = 0; r < 4; r++) {
                const float s = sc[b2*4 + r];
                const float e = fexp2(s);
                const float hs = __builtin_amdgcn_fmed3f(s*HSC2 + 0.5f, 0.f, 1.f);
                ww[r] = e*hs;
            }
            gacc += (ww[0] + ww[1]) + (ww[2] + ww[3]);
            asm("v_cvt_pk_bf16_f32 %0, %1, %2" : "=v"(u[b2][0]) : "v"(ww[0]), "v"(ww[1]));
            asm("v_cvt_pk_bf16_f32 %0, %1, %2" : "=v"(u[b2][1]) : "v"(ww[2]), "v"(ww[3]));
        }
        #pragma unroll
        for (int c16 = 0; c16 < 2; c16++) {
            u32 x0 = u[2*c16][0], y0 = u[2*c16+1][0];
            u32 x1 = u[2*c16][1], y1 = u[2*c16+1][1];
            asm("v_permlane32_swap_b32 %0, %1" : "+v"(x0), "+v"(y0));
            asm("v_permlane32_swap_b32 %0, %1" : "+v"(x1), "+v"(y1));
            union { u32 uu[4]; s16x8 v; } pa;
            pa.uu[0] = x0; pa.uu[1] = x1; pa.uu[2] = y0; pa.uu[3] = y1;
            const int ccv = kb*4 + c16*2 + hi;
            s16x8 vf0 = *(const s16x8*)&Vc[(size_t)ln*64        + (ccv ^ l7)*8];
            s16x8 vf1 = *(const s16x8*)&Vc[(size_t)(32 + ln)*64 + (ccv ^ l7)*8];
            __builtin_amdgcn_s_setprio(1);
            o0 = mfma32(pa.v, vf0, o0);
            o1 = mfma32(pa.v, vf1, o1);
            __builtin_amdgcn_s_setprio(0);
        }
    }
}

// ---------------- fused flash attention, split-K(8): 2048 blocks, 32KB LDS, 5 blocks/CU ----------------
// Each block: 128 q x 256 keys (4 tiles of 64). Double-buffered staging; 2x residency passes
// smooth the dispatch tail that capped the split-K(4) kernel.
__global__ __launch_bounds__(256) void attn_split8(const u16* __restrict__ q, const u16* __restrict__ k,
                                                   const u16* __restrict__ vt,
                                                   u16* __restrict__ opart, float* __restrict__ gpart) {
    __shared__ u16 Ks[2][64*64];
    __shared__ u16 Vs[2][64*64];
    const int bid = blockIdx.x;
    const int xcd = bid & 7, j = bid >> 3;      // j: 0..255
    const int g16 = j >> 4, qt = j & 15;        // 16 (bh,ks) groups per XCD, 16 q-tiles each
    const int bhks = xcd*16 + g16;              // 0..127
    const int bh = bhks >> 3, ks = bhks & 7;
    const int b = bh >> 3, h = bh & 7;
    const int qb0 = qt * 128;
    const int t = threadIdx.x;
    const int w = t >> 6, l = t & 63;
    const int ln = l & 31, hi = l >> 5, l7 = l & 7;

    const size_t qrow = (size_t)(b*SEQ + qb0 + w*32 + ln);
    s16x8 qf[4];
    #pragma unroll
    for (int c = 0; c < 4; c++)
        qf[c] = *(const s16x8*)(q + qrow*DIMD + h*HDIM + c*16 + hi*8);

    const int sr = l >> 3;
    const int swc = ((l & 7) ^ sr) * 8;
    const u16* ksrc = k  + (size_t)(b*SEQ + ks*256 + w*16 + sr)*DIMD + h*HDIM + swc;
    const u16* vsrc = vt + (size_t)bh*HDIM*SEQ + (size_t)(w*16 + sr)*SEQ + ks*256 + swc;
    const int ldsw = w*1024;

    f32x16 o0 = {}, o1 = {};
    float gacc = 0.f;

    // prologue: stage key-tile 0 (64 keys)
    #pragma unroll
    for (int g = 0; g < 2; g++) {
        GLDS16(ksrc + (size_t)g*8*DIMD, &Ks[0][ldsw + g*512]);
        GLDS16(vsrc + (size_t)g*8*SEQ,  &Vs[0][ldsw + g*512]);
    }
    __syncthreads();

    #pragma unroll 1
    for (int tp = 0; tp < 2; ++tp) {
        const int tt0 = tp*2;
        {
            const int adv = (tt0 + 1) * 64;
            #pragma unroll
            for (int g = 0; g < 2; g++) {
                GLDS16(ksrc + (size_t)(adv)*DIMD + (size_t)g*8*DIMD, &Ks[1][ldsw + g*512]);
                GLDS16(vsrc + (size_t)g*8*SEQ + adv,                 &Vs[1][ldsw + g*512]);
            }
        }
        attn_phase64(&Ks[0][0], &Vs[0][0], qf, o0, o1, gacc, ln, hi, l7);
        __syncthreads();
        if (tp < 1) {
            const int adv = (tt0 + 2) * 64;
            #pragma unroll
            for (int g = 0; g < 2; g++) {
                GLDS16(ksrc + (size_t)(adv)*DIMD + (size_t)g*8*DIMD, &Ks[0][ldsw + g*512]);
                GLDS16(vsrc + (size_t)g*8*SEQ + adv,                 &Vs[0][ldsw + g*512]);
            }
        }
        attn_phase64(&Ks[1][0], &Vs[1][0], qf, o0, o1, gacc, ln, hi, l7);
        __syncthreads();
    }

    gacc += __shfl_xor(gacc, 32);
    if (l < 32)
        gpart[((size_t)ks*16 + bh)*SEQ + qb0 + w*32 + l] = gacc;

    u16* op = opart + ((size_t)ks*MROWS + b*SEQ + qb0 + w*32)*DIMD + h*HDIM;
    #pragma unroll
    for (int i = 0; i < 16; i++) {
        const int qr = (i & 3) + 8*(i >> 2) + 4*hi;
        op[(size_t)qr*DIMD + ln]      = f2bf(o0[i]);
        op[(size_t)qr*DIMD + 32 + ln] = f2bf(o1[i]);
    }
}

// ---------------- softsign + softshrink residual + LayerNorm (bf16 proj in) ----------------
__global__ __launch_bounds__(256) void ln_epilogue(const u16* __restrict__ proj, const float* __restrict__ x,
                                                   const float* __restrict__ gamma, const float* __restrict__ beta,
                                                   float* __restrict__ out) {
    const int row = blockIdx.x*4 + (threadIdx.x >> 6);
    const int l = threadIdx.x & 63;
    const u16* pr = proj + (size_t)row*DIMD + l*8;
    const float* xr = x  + (size_t)row*DIMD + l*8;
    s16x8 pv = *(const s16x8*)pr;
    float tv[8];
    float s = 0.f, s2 = 0.f;
    #pragma unroll
    for (int j = 0; j < 2; j++) {
        float4 xv = *(const float4*)(xr + j*4);
        float xa[4] = {xv.x, xv.y, xv.z, xv.w};
        #pragma unroll
        for (int qq = 0; qq < 4; qq++) {
            const float p = bf2f((u16)pv[j*4+qq]);
            const float ss = p / (1.f + fabsf(p));
            const float xx = xa[qq];
            const float sh = xx > 0.5f ? xx - 0.5f : (xx < -0.5f ? xx + 0.5f : 0.f);
            const float tt = ss + sh;
            tv[j*4+qq] = tt; s += tt; s2 += tt*tt;
        }
    }
    #pragma unroll
    for (int m = 1; m < 64; m <<= 1) { s += __shfl_xor(s, m); s2 += __shfl_xor(s2, m); }
    const float mu = s * (1.f/512.f);
    float var = s2 * (1.f/512.f) - mu*mu;
    const float rstd = rsqrtf(var + 1e-5f);
    #pragma unroll
    for (int j = 0; j < 2; j++) {
        float4 g  = *(const float4*)(gamma + l*8 + j*4);
        float4 bb = *(const float4*)(beta  + l*8 + j*4);
        float4 ov;
        ov.x = (tv[j*4+0]-mu)*rstd*g.x + bb.x;
        ov.y = (tv[j*4+1]-mu)*rstd*g.y + bb.y;
        ov.z = (tv[j*4+2]-mu)*rstd*g.z + bb.z;
        ov.w = (tv[j*4+3]-mu)*rstd*g.w + bb.w;
        *(float4*)(out + (size_t)row*DIMD + l*8 + j*4) = ov;
    }
}

extern "C" void kernel_launch(void* const* d_in, const int* in_sizes, int n_in,
                              void* d_out, int out_size, void* d_ws, size_t ws_size,
                              hipStream_t stream) {
    const float* x     = (const float*)d_in[0];
    const float* Wq    = (const float*)d_in[1];
    const float* Wk    = (const float*)d_in[2];
    const float* Wv    = (const float*)d_in[3];
    const float* Wo    = (const float*)d_in[4];
    const float* gamma = (const float*)d_in[5];
    const float* beta  = (const float*)d_in[6];
    float* out = (float*)d_out;
    char* ws = (char*)d_ws;

    u16* xb    = (u16*)(ws);                               // 4 MB
    u16* wqkvb = (u16*)(ws + (4<<20));                     // 1.5 MB  [1536,512]
    u16* wob   = (u16*)(ws + (4<<20) + (1536<<10));        // 0.5 MB
    u16* qb    = (u16*)(ws + (6<<20));                     // 4 MB
    u16* kb    = (u16*)(ws + (10<<20));                    // 4 MB
    u16* vtb   = (u16*)(ws + (14<<20));                    // 4 MB
    float* gpart = (float*)(ws + (18<<20));                // 1 MB (ex-ab slot) [<=8][16][2048] f32
    u16* proj  = (u16*)(ws + (22<<20));                    // 4 MB (bf16)
    u16* opart = (u16*)(ws + (26<<20));                    // 16 MB (NS=4) / 32 MB (NS=8) bf16

    cvt_all<<<3072, 256, 0, stream>>>(x, Wq, Wk, Wv, Wo, xb, wqkvb, wob);

    gemm128x64<3><<<dim3(MROWS/128, 1536/64), 256, 0, stream>>>(xb, wqkvb, qb, kb, vtb, MROWS, 1536, DIMD);

    const size_t need8 = ((size_t)26 << 20) + ((size_t)32 << 20);   // opart end at 58 MB
    if (ws_size >= need8) {
        // split-K 8: 2048 blocks (2 residency passes, 5 blocks/CU by 32KB LDS)
        attn_split8<<<2048, 256, 0, stream>>>(qb, kb, vtb, opart, gpart);
        gemm_bt2f<8><<<dim3(MROWS/32, DIMD/64), 256, 0, stream>>>(opart, gpart, wob, proj);
    } else {
        // proven fallback: split-K 4 pipelined
        attn_split<<<1024, 256, 0, stream>>>(qb, kb, vtb, opart, gpart);
        gemm_bt2f<4><<<dim3(MROWS/32, DIMD/64), 256, 0, stream>>>(opart, gpart, wob, proj);
    }

    ln_epilogue<<<MROWS/4, 256, 0, stream>>>(proj, x, gamma, beta, out);
}

// Round 13
// 63.876 us; speedup vs baseline: 1.1472x; 1.1472x over previous
//
#include <hip/hip_runtime.h>

#define DIMD 512
#define NB 2
#define SEQ 2048
#define NHEADS 8
#define HDIM 64
#define MROWS (NB*SEQ)   // 4096

typedef short s16x8 __attribute__((ext_vector_type(8)));
typedef float f32x4 __attribute__((ext_vector_type(4)));
typedef float f32x16 __attribute__((ext_vector_type(16)));
typedef unsigned short u16;
typedef unsigned int u32;

__device__ __forceinline__ u16 f2bf(float f) {
    union { float f; u32 u; } c; c.f = f;
    u32 u = c.u;
    return (u16)((u + 0x7FFFu + ((u >> 16) & 1u)) >> 16);
}
__device__ __forceinline__ float bf2f(u16 v) {
    union { u32 u; float f; } c; c.u = ((u32)v) << 16;
    return c.f;
}

__device__ __forceinline__ f32x4 mfma16(s16x8 a, s16x8 b, f32x4 c) {
    return __builtin_amdgcn_mfma_f32_16x16x32_bf16(a, b, c, 0, 0, 0);
}
__device__ __forceinline__ f32x16 mfma32(s16x8 a, s16x8 b, f32x16 c) {
    return __builtin_amdgcn_mfma_f32_32x32x16_bf16(a, b, c, 0, 0, 0);
}
// Raw v_exp_f32: exact for |x| << 126 (scores are O(5)); 1 TRANS instr vs libm's ~6 VALU.
__device__ __forceinline__ float fexp2(float x) {
    float r; asm("v_exp_f32 %0, %1" : "=v"(r) : "v"(x)); return r;
}
__device__ __forceinline__ float frcp(float x) {
    float r; asm("v_rcp_f32 %0, %1" : "=v"(r) : "v"(x)); return r;
}

#define GLDS16(g, l) __builtin_amdgcn_global_load_lds( \
    (const __attribute__((address_space(1))) void*)(g), \
    (__attribute__((address_space(3))) void*)(l), 16, 0, 0)

#define ESCF 0.180336880111f   // 0.125 * log2(e), folded into Q at GEMM epilogue
#define HSC2 0.115524530f      // (0.125/6) / ESCF

// ---------------- fp32 -> bf16 convert: x + all four weights, one launch ----------------
__global__ void cvt_all(const float* __restrict__ x, const float* __restrict__ Wq,
                        const float* __restrict__ Wk, const float* __restrict__ Wv,
                        const float* __restrict__ Wo,
                        u16* __restrict__ xb, u16* __restrict__ wqkv, u16* __restrict__ wo) {
    int i = blockIdx.x * blockDim.x + threadIdx.x;   // 0..786431
    const float* src; u16* dst; int idx;
    if (i < 524288) { src = x; dst = xb; idx = i; }
    else {
        int jj = i - 524288;
        int which = jj >> 16; idx = jj & 65535;
        src = which == 0 ? Wq : which == 1 ? Wk : which == 2 ? Wv : Wo;
        dst = which < 3 ? wqkv + which*DIMD*DIMD : wo;
    }
    float4 v = reinterpret_cast<const float4*>(src)[idx];
    ushort4 o;
    o.x = f2bf(v.x); o.y = f2bf(v.y); o.z = f2bf(v.z); o.w = f2bf(v.w);
    reinterpret_cast<ushort4*>(dst)[idx] = o;
}

// ---------------- 128x64 GEMM: C = A[M,K] @ B[N,K]^T, 3 blocks/CU at this shape ----------------
// WMODE 3: QKV merged, N=1536; region0 q (pre-scaled ESCF), region1 k, region2 vt[b][h][d][s].
template<int WMODE>
__global__ __launch_bounds__(256) void gemm128x64(const u16* __restrict__ A, const u16* __restrict__ Bm,
                                                  void* __restrict__ Cout, void* __restrict__ Cout2,
                                                  void* __restrict__ Cout3, int M, int N, int K) {
    __shared__ u16 As[128*64];
    __shared__ u16 Bs[64*64];
    const int bm0 = blockIdx.x * 128, bn0 = blockIdx.y * 64;
    const int t = threadIdx.x;
    const int w = t >> 6, l = t & 63;
    const int lg = l >> 4, lr = l & 15;
    f32x4 acc[2][4] = {};
    const int sr8 = l >> 3;
    const int swc = ((l & 7) ^ (sr8 & 7)) * 8;
    const int arow = w*32 + sr8;                 // A: wave w stages rows w*32 + g*8 + sr8
    const int brow = w*8 + sr8;                  // B: stages rows g*32 + w*8 + sr8
    const u16* asrc = A  + (size_t)(bm0 + arow)*K + swc;
    const u16* bsrc = Bm + (size_t)(bn0 + brow)*K + swc;

    for (int k0 = 0; k0 < K; k0 += 64) {
        #pragma unroll
        for (int g = 0; g < 4; g++)
            GLDS16(asrc + (size_t)g*8*K + k0, &As[w*2048 + g*512]);
        #pragma unroll
        for (int g = 0; g < 2; g++)
            GLDS16(bsrc + (size_t)g*32*K + k0, &Bs[g*2048 + w*512]);
        __syncthreads();
        #pragma unroll
        for (int ks = 0; ks < 2; ks++) {
            const int swr = ((ks*4 + lg) ^ (lr & 7)) * 8;
            s16x8 af[2], bfr[4];
            #pragma unroll
            for (int fm = 0; fm < 2; fm++)
                af[fm] = *(const s16x8*)&As[(w*32 + fm*16 + lr)*64 + swr];
            #pragma unroll
            for (int fn = 0; fn < 4; fn++)
                bfr[fn] = *(const s16x8*)&Bs[(fn*16 + lr)*64 + swr];
            #pragma unroll
            for (int fm = 0; fm < 2; fm++)
                #pragma unroll
                for (int fn = 0; fn < 4; fn++)
                    acc[fm][fn] = mfma16(af[fm], bfr[fn], acc[fm][fn]);
        }
        __syncthreads();
    }

    const int region = (WMODE == 3) ? (bn0 >> 9) : 0;
    const float qsc = (WMODE == 3 && region == 0) ? ESCF : 1.0f;
    #pragma unroll
    for (int fm = 0; fm < 2; fm++) {
        #pragma unroll
        for (int fn = 0; fn < 4; fn++) {
            const int mb = bm0 + w*32 + fm*16 + lg*4;
            const int n  = bn0 + fn*16 + lr;
            if (WMODE == 2) {
                float* C = (float*)Cout;
                #pragma unroll
                for (int i = 0; i < 4; i++)
                    C[(size_t)(mb + i)*N + n] = acc[fm][fn][i];
            } else {
                const int nl = n & 511;
                if (region == 2) {
                    const int b = mb >> 11, s0 = mb & 2047;
                    const int h = nl >> 6, d = nl & 63;
                    ushort4 pk;
                    pk.x = f2bf(acc[fm][fn][0]);
                    pk.y = f2bf(acc[fm][fn][1]);
                    pk.z = f2bf(acc[fm][fn][2]);
                    pk.w = f2bf(acc[fm][fn][3]);
                    *(ushort4*)((u16*)Cout3 + (size_t)((b*8 + h)*64 + d)*2048 + s0) = pk;
                } else {
                    u16* C = region == 0 ? (u16*)Cout : (u16*)Cout2;
                    #pragma unroll
                    for (int i = 0; i < 4; i++)
                        C[(size_t)(mb + i)*512 + nl] = f2bf(acc[fm][fn][i] * qsc);
                }
            }
        }
    }
}

// ---------------- fused: combine split-K partials + normalize + Wo GEMM (32x64 tile) ----------------
// 1024 blocks = 4 blocks/CU; grid_y = 8 keeps A-combine duplication unchanged vs 64x64.
__global__ __launch_bounds__(256) void gemm_bt2f(const u16* __restrict__ opart,
                                                 const float* __restrict__ gpart,
                                                 const u16* __restrict__ Bm,
                                                 u16* __restrict__ Cout) {
    __shared__ u16 As[32*64];
    __shared__ u16 Bs[64*64];
    __shared__ float ginv[32][9];   // +1 pad: spread banks
    const int bm0 = blockIdx.x * 32, bn0 = blockIdx.y * 64;
    const int t = threadIdx.x;
    const int w = t >> 6, l = t & 63;
    const int lg = l >> 4, lr = l & 15;
    const int wm = w >> 1, wn = w & 1;
    f32x4 acc[2] = {};
    const int srow = t >> 3;            // 0..31
    const int c8 = t & 7;
    const int scol = c8 * 8;
    const int swz = (c8 ^ (srow & 7)) * 8;   // swizzled chunk (write pos for A, src col for B)

    // precompute 1/denominator for the 32 rows x 8 heads this block touches (256 = 1/thread)
    {
        const int r = t >> 3, h = t & 7;
        const int rg = bm0 + r;
        const int b = rg >> 11, s = rg & 2047;
        float g = gpart[(size_t)(b*8 + h)*SEQ + s]
                + gpart[(size_t)(16 + b*8 + h)*SEQ + s]
                + gpart[(size_t)(32 + b*8 + h)*SEQ + s]
                + gpart[(size_t)(48 + b*8 + h)*SEQ + s];
        ginv[r][h] = frcp(g);
    }
    __syncthreads();

    for (int k0 = 0; k0 < DIMD; k0 += 64) {
        const int h = k0 >> 6;          // head of this k-slab (cols k0..k0+63)
        // B: async staged, source pre-swizzled -> linear LDS holds col p^(row&7) at pos p
        #pragma unroll
        for (int c = 0; c < 2; c++) {
            const u16* gb = Bm + (size_t)(bn0 + c*32 + srow)*DIMD + k0 + swz;
            GLDS16(gb, (char*)Bs + c*4096 + w*1024);
        }
        // A: reg-staged fused normalize of 4 partials (32 rows, 1 chunk/thread)
        {
            const int rl = srow;
            const int rg = bm0 + rl;
            const u16* oprow = opart + (size_t)rg*DIMD + k0 + scol;
            s16x8 p0 = *(const s16x8*)(oprow);
            s16x8 p1 = *(const s16x8*)(oprow + (size_t)MROWS*DIMD);
            s16x8 p2 = *(const s16x8*)(oprow + (size_t)2*MROWS*DIMD);
            s16x8 p3 = *(const s16x8*)(oprow + (size_t)3*MROWS*DIMD);
            const float inv = ginv[rl][h];
            union { u32 uu[4]; s16x8 v; } av;
            #pragma unroll
            for (int e2 = 0; e2 < 4; e2++) {
                const float s0 = (bf2f((u16)p0[2*e2]) + bf2f((u16)p1[2*e2]))
                               + (bf2f((u16)p2[2*e2]) + bf2f((u16)p3[2*e2]));
                const float s1 = (bf2f((u16)p0[2*e2+1]) + bf2f((u16)p1[2*e2+1]))
                               + (bf2f((u16)p2[2*e2+1]) + bf2f((u16)p3[2*e2+1]));
                asm("v_cvt_pk_bf16_f32 %0, %1, %2" : "=v"(av.uu[e2]) : "v"(s0*inv), "v"(s1*inv));
            }
            *(s16x8*)&As[rl*64 + swz] = av.v;
        }
        __syncthreads();
        #pragma unroll
        for (int ks = 0; ks < 2; ks++) {
            const int rc = ((ks*4 + lg) ^ (lr & 7)) * 8;
            s16x8 af = *(const s16x8*)&As[(wm*16 + lr)*64 + rc];
            s16x8 bfr[2];
            #pragma unroll
            for (int fn = 0; fn < 2; fn++)
                bfr[fn] = *(const s16x8*)&Bs[(wn*32 + fn*16 + lr)*64 + rc];
            #pragma unroll
            for (int fn = 0; fn < 2; fn++)
                acc[fn] = mfma16(af, bfr[fn], acc[fn]);
        }
        __syncthreads();
    }

    #pragma unroll
    for (int fn = 0; fn < 2; fn++) {
        const int mb = bm0 + wm*16 + lg*4;
        const int n  = bn0 + wn*32 + fn*16 + lr;
        #pragma unroll
        for (int i = 0; i < 4; i++)
            Cout[(size_t)(mb + i)*DIMD + n] = f2bf(acc[fn][i]);
    }
}

// ---------------- fused flash attention, split-K(4), cross-tile pipelined (best measured) ----------------
// Tiles t=0..7 (64 keys each). K triple-buffered (staged 2 ahead), V double-buffered
// (staged 1 ahead). SM/PV of tile t-1 runs under QK(t)'s MFMAs; counted vmcnt never
// drains prefetch in steady state.
__global__ __launch_bounds__(256) void attn_split(const u16* __restrict__ q, const u16* __restrict__ k,
                                                  const u16* __restrict__ vt,
                                                  u16* __restrict__ opart, float* __restrict__ gpart) {
    __shared__ u16 Ks[3][64*64];
    __shared__ u16 Vs[2][64*64];
    const int bid = blockIdx.x;
    const int xcd = bid & 7, j = bid >> 3;      // j: 0..127
    const int g8 = j >> 4, qt = j & 15;         // 8 (bh,ks) groups per XCD, 16 q-tiles each
    const int bhks = xcd*8 + g8;                // 0..63
    const int bh = bhks >> 2, ks = bhks & 3;
    const int b = bh >> 3, h = bh & 7;
    const int qb0 = qt * 128;
    const int t = threadIdx.x;
    const int w = t >> 6, l = t & 63;
    const int ln = l & 31, hi = l >> 5, l7 = l & 7;

    // Q B-fragments: wave w owns q-rows qb0 + w*32 + ln (pre-scaled by ESCF)
    const size_t qrow = (size_t)(b*SEQ + qb0 + w*32 + ln);
    s16x8 qf[4];
    #pragma unroll
    for (int c = 0; c < 4; c++)
        qf[c] = *(const s16x8*)(q + qrow*DIMD + h*HDIM + c*16 + hi*8);

    // staging: wave w stages rows w*16 + g*8 + (l>>3); row&7 == l>>3 -> same XOR chunk
    const int sr = l >> 3;
    const int swc = ((l & 7) ^ sr) * 8;
    const u16* ksrc = k  + (size_t)(b*SEQ + ks*512 + w*16 + sr)*DIMD + h*HDIM + swc;
    const u16* vsrc = vt + (size_t)bh*HDIM*SEQ + (size_t)(w*16 + sr)*SEQ + ks*512 + swc;
    const int ldsw = w*1024;

    f32x16 o0 = {}, o1 = {};
    float gacc = 0.f;

#define SV(T, B) do { GLDS16(vsrc + (T)*64,                 &Vs[B][ldsw]); \
                      GLDS16(vsrc + (size_t)8*SEQ + (T)*64, &Vs[B][ldsw + 512]); } while(0)
#define SK(T, B) do { GLDS16(ksrc + (size_t)((T)*64)*DIMD,     &Ks[B][ldsw]); \
                      GLDS16(ksrc + (size_t)((T)*64 + 8)*DIMD, &Ks[B][ldsw + 512]); } while(0)
#define WB(N) do { asm volatile("s_waitcnt vmcnt(" #N ")" ::: "memory"); \
                   __builtin_amdgcn_s_barrier(); \
                   asm volatile("" ::: "memory"); } while(0)
#define QKH(B, KB, SC) do { SC = (f32x16){}; \
    __builtin_amdgcn_s_setprio(1); \
    _Pragma("unroll") for (int c_ = 0; c_ < 4; c_++) { \
        const int ch_ = (((c_ << 1) | hi) ^ l7) * 8; \
        s16x8 kf_ = *(const s16x8*)&Ks[B][((KB)*32 + ln)*64 + ch_]; \
        SC = mfma32(kf_, qf[c_], SC); } \
    __builtin_amdgcn_s_setprio(0); } while(0)
#define SMPV(SC, KB, VB) do { \
    u32 up_[4][2]; \
    _Pragma("unroll") for (int b2_ = 0; b2_ < 4; b2_++) { \
        const float s0_ = SC[b2_*4+0], s1_ = SC[b2_*4+1]; \
        const float s2_ = SC[b2_*4+2], s3_ = SC[b2_*4+3]; \
        const float w0_ = fexp2(s0_) * __builtin_amdgcn_fmed3f(s0_*HSC2 + 0.5f, 0.f, 1.f); \
        const float w1_ = fexp2(s1_) * __builtin_amdgcn_fmed3f(s1_*HSC2 + 0.5f, 0.f, 1.f); \
        const float w2_ = fexp2(s2_) * __builtin_amdgcn_fmed3f(s2_*HSC2 + 0.5f, 0.f, 1.f); \
        const float w3_ = fexp2(s3_) * __builtin_amdgcn_fmed3f(s3_*HSC2 + 0.5f, 0.f, 1.f); \
        gacc += (w0_ + w1_) + (w2_ + w3_); \
        asm("v_cvt_pk_bf16_f32 %0, %1, %2" : "=v"(up_[b2_][0]) : "v"(w0_), "v"(w1_)); \
        asm("v_cvt_pk_bf16_f32 %0, %1, %2" : "=v"(up_[b2_][1]) : "v"(w2_), "v"(w3_)); } \
    _Pragma("unroll") for (int c16_ = 0; c16_ < 2; c16_++) { \
        u32 x0_ = up_[2*c16_][0], y0_ = up_[2*c16_+1][0]; \
        u32 x1_ = up_[2*c16_][1], y1_ = up_[2*c16_+1][1]; \
        asm("v_permlane32_swap_b32 %0, %1" : "+v"(x0_), "+v"(y0_)); \
        asm("v_permlane32_swap_b32 %0, %1" : "+v"(x1_), "+v"(y1_)); \
        union { u32 w[4]; s16x8 v; } pa_; \
        pa_.w[0] = x0_; pa_.w[1] = x1_; pa_.w[2] = y0_; pa_.w[3] = y1_; \
        const int ccv_ = (KB)*4 + c16_*2 + hi; \
        s16x8 vf0_ = *(const s16x8*)&Vs[VB][(size_t)ln*64        + (ccv_ ^ l7)*8]; \
        s16x8 vf1_ = *(const s16x8*)&Vs[VB][(size_t)(32 + ln)*64 + (ccv_ ^ l7)*8]; \
        __builtin_amdgcn_s_setprio(1); \
        o0 = mfma32(pa_.v, vf0_, o0); \
        o1 = mfma32(pa_.v, vf1_, o1); \
        __builtin_amdgcn_s_setprio(0); } } while(0)

    f32x16 a0, a1, b0, b1;
    // prologue: V(0), K(0), K(1)
    SV(0,0); SK(0,0); SK(1,1);
    WB(2);                                   // V0,K0 done; K1 may fly
    QKH(0,0,a0); SK(2,2); QKH(0,1,a1);       // iter 0 (no SMPV)
    WB(2);                                   // ..K1 done (newest-2 = K2)
    SV(1,1); QKH(1,0,b0); SK(3,0); SMPV(a0,0,0); QKH(1,1,b1); SMPV(a1,1,0);
    WB(2);                                   // V1,K2 done (newest-2 = K3)
    SV(2,0); QKH(2,0,a0); SK(4,1); SMPV(b0,0,1); QKH(2,1,a1); SMPV(b1,1,1);
    WB(2);
    SV(3,1); QKH(0,0,b0); SK(5,2); SMPV(a0,0,0); QKH(0,1,b1); SMPV(a1,1,0);
    WB(2);
    SV(4,0); QKH(1,0,a0); SK(6,0); SMPV(b0,0,1); QKH(1,1,a1); SMPV(b1,1,1);
    WB(2);
    SV(5,1); QKH(2,0,b0); SK(7,1); SMPV(a0,0,0); QKH(2,1,b1); SMPV(a1,1,0);
    WB(2);
    SV(6,0); QKH(0,0,a0); SMPV(b0,0,1); QKH(0,1,a1); SMPV(b1,1,1);
    WB(0);                                   // V6 was newest outstanding
    SV(7,1); QKH(1,0,b0); SMPV(a0,0,0); QKH(1,1,b1); SMPV(a1,1,0);
    WB(0);                                   // V7 done everywhere
    SMPV(b0,0,1); SMPV(b1,1,1);

#undef SV
#undef SK
#undef WB
#undef QKH
#undef SMPV

    // partial denominator (sum over this key-split), q lives in lanes l and l^32
    gacc += __shfl_xor(gacc, 32);
    if (l < 32)
        gpart[((size_t)ks*16 + bh)*SEQ + qb0 + w*32 + l] = gacc;

    // partial output (unnormalized, bf16)
    u16* op = opart + ((size_t)ks*MROWS + b*SEQ + qb0 + w*32)*DIMD + h*HDIM;
    #pragma unroll
    for (int i = 0; i < 16; i++) {
        const int qr = (i & 3) + 8*(i >> 2) + 4*hi;
        op[(size_t)qr*DIMD + ln]      = f2bf(o0[i]);
        op[(size_t)qr*DIMD + 32 + ln] = f2bf(o1[i]);
    }
}

// ---------------- softsign + softshrink residual + LayerNorm (bf16 proj in) ----------------
__global__ __launch_bounds__(256) void ln_epilogue(const u16* __restrict__ proj, const float* __restrict__ x,
                                                   const float* __restrict__ gamma, const float* __restrict__ beta,
                                                   float* __restrict__ out) {
    const int row = blockIdx.x*4 + (threadIdx.x >> 6);
    const int l = threadIdx.x & 63;
    const u16* pr = proj + (size_t)row*DIMD + l*8;
    const float* xr = x  + (size_t)row*DIMD + l*8;
    s16x8 pv = *(const s16x8*)pr;
    float tv[8];
    float s = 0.f, s2 = 0.f;
    #pragma unroll
    for (int j = 0; j < 2; j++) {
        float4 xv = *(const float4*)(xr + j*4);
        float xa[4] = {xv.x, xv.y, xv.z, xv.w};
        #pragma unroll
        for (int qq = 0; qq < 4; qq++) {
            const float p = bf2f((u16)pv[j*4+qq]);
            const float ss = p / (1.f + fabsf(p));
            const float xx = xa[qq];
            const float sh = xx > 0.5f ? xx - 0.5f : (xx < -0.5f ? xx + 0.5f : 0.f);
            const float tt = ss + sh;
            tv[j*4+qq] = tt; s += tt; s2 += tt*tt;
        }
    }
    #pragma unroll
    for (int m = 1; m < 64; m <<= 1) { s += __shfl_xor(s, m); s2 += __shfl_xor(s2, m); }
    const float mu = s * (1.f/512.f);
    float var = s2 * (1.f/512.f) - mu*mu;
    const float rstd = rsqrtf(var + 1e-5f);
    #pragma unroll
    for (int j = 0; j < 2; j++) {
        float4 g  = *(const float4*)(gamma + l*8 + j*4);
        float4 bb = *(const float4*)(beta  + l*8 + j*4);
        float4 ov;
        ov.x = (tv[j*4+0]-mu)*rstd*g.x + bb.x;
        ov.y = (tv[j*4+1]-mu)*rstd*g.y + bb.y;
        ov.z = (tv[j*4+2]-mu)*rstd*g.z + bb.z;
        ov.w = (tv[j*4+3]-mu)*rstd*g.w + bb.w;
        *(float4*)(out + (size_t)row*DIMD + l*8 + j*4) = ov;
    }
}

extern "C" void kernel_launch(void* const* d_in, const int* in_sizes, int n_in,
                              void* d_out, int out_size, void* d_ws, size_t ws_size,
                              hipStream_t stream) {
    const float* x     = (const float*)d_in[0];
    const float* Wq    = (const float*)d_in[1];
    const float* Wk    = (const float*)d_in[2];
    const float* Wv    = (const float*)d_in[3];
    const float* Wo    = (const float*)d_in[4];
    const float* gamma = (const float*)d_in[5];
    const float* beta  = (const float*)d_in[6];
    float* out = (float*)d_out;
    char* ws = (char*)d_ws;

    u16* xb    = (u16*)(ws);                               // 4 MB
    u16* wqkvb = (u16*)(ws + (4<<20));                     // 1.5 MB  [1536,512]
    u16* wob   = (u16*)(ws + (4<<20) + (1536<<10));        // 0.5 MB
    u16* qb    = (u16*)(ws + (6<<20));                     // 4 MB
    u16* kb    = (u16*)(ws + (10<<20));                    // 4 MB
    u16* vtb   = (u16*)(ws + (14<<20));                    // 4 MB
    u16* proj  = (u16*)(ws + (22<<20));                    // 4 MB (bf16)
    u16* opart = (u16*)(ws + (26<<20));                    // 16 MB [4][4096][512] bf16
    float* gpart = (float*)(ws + (42<<20));                // 512 KB [4][16][2048] f32

    cvt_all<<<3072, 256, 0, stream>>>(x, Wq, Wk, Wv, Wo, xb, wqkvb, wob);

    // 768 blocks = 3/CU (was 384 = 1.5/CU at 128x128)
    gemm128x64<3><<<dim3(MROWS/128, 1536/64), 256, 0, stream>>>(xb, wqkvb, qb, kb, vtb, MROWS, 1536, DIMD);

    // 1024 blocks: 8 XCD x 8 (bh,ks) groups x 16 q-tiles, 4 blocks/CU
    attn_split<<<1024, 256, 0, stream>>>(qb, kb, vtb, opart, gpart);

    // fused combine + Wo projection, 32x64 tile: 1024 blocks = 4/CU
    gemm_bt2f<<<dim3(MROWS/32, DIMD/64), 256, 0, stream>>>(opart, gpart, wob, proj);

    ln_epilogue<<<MROWS/4, 256, 0, stream>>>(proj, x, gamma, beta, out);
}

// Round 14
// 62.854 us; speedup vs baseline: 1.1659x; 1.0163x over previous
//
#include <hip/hip_runtime.h>

#define DIMD 512
#define NB 2
#define SEQ 2048
#define NHEADS 8
#define HDIM 64
#define MROWS (NB*SEQ)   // 4096

typedef short s16x8 __attribute__((ext_vector_type(8)));
typedef float f32x4 __attribute__((ext_vector_type(4)));
typedef float f32x16 __attribute__((ext_vector_type(16)));
typedef unsigned short u16;
typedef unsigned int u32;

__device__ __forceinline__ u16 f2bf(float f) {
    union { float f; u32 u; } c; c.f = f;
    u32 u = c.u;
    return (u16)((u + 0x7FFFu + ((u >> 16) & 1u)) >> 16);
}
__device__ __forceinline__ float bf2f(u16 v) {
    union { u32 u; float f; } c; c.u = ((u32)v) << 16;
    return c.f;
}

__device__ __forceinline__ f32x4 mfma16(s16x8 a, s16x8 b, f32x4 c) {
    return __builtin_amdgcn_mfma_f32_16x16x32_bf16(a, b, c, 0, 0, 0);
}
__device__ __forceinline__ f32x16 mfma32(s16x8 a, s16x8 b, f32x16 c) {
    return __builtin_amdgcn_mfma_f32_32x32x16_bf16(a, b, c, 0, 0, 0);
}
// Raw v_exp_f32: exact for |x| << 126 (scores are O(5)); 1 TRANS instr vs libm's ~6 VALU.
__device__ __forceinline__ float fexp2(float x) {
    float r; asm("v_exp_f32 %0, %1" : "=v"(r) : "v"(x)); return r;
}
__device__ __forceinline__ float frcp(float x) {
    float r; asm("v_rcp_f32 %0, %1" : "=v"(r) : "v"(x)); return r;
}

#define GLDS16(g, l) __builtin_amdgcn_global_load_lds( \
    (const __attribute__((address_space(1))) void*)(g), \
    (__attribute__((address_space(3))) void*)(l), 16, 0, 0)

#define ESCF 0.180336880111f   // 0.125 * log2(e), folded into Q at GEMM epilogue
#define HSC2 0.115524530f      // (0.125/6) / ESCF

// ---------------- fp32 -> bf16 convert: x + all four weights, one launch ----------------
__global__ void cvt_all(const float* __restrict__ x, const float* __restrict__ Wq,
                        const float* __restrict__ Wk, const float* __restrict__ Wv,
                        const float* __restrict__ Wo,
                        u16* __restrict__ xb, u16* __restrict__ wqkv, u16* __restrict__ wo) {
    int i = blockIdx.x * blockDim.x + threadIdx.x;   // 0..786431
    const float* src; u16* dst; int idx;
    if (i < 524288) { src = x; dst = xb; idx = i; }
    else {
        int jj = i - 524288;
        int which = jj >> 16; idx = jj & 65535;
        src = which == 0 ? Wq : which == 1 ? Wk : which == 2 ? Wv : Wo;
        dst = which < 3 ? wqkv + which*DIMD*DIMD : wo;
    }
    float4 v = reinterpret_cast<const float4*>(src)[idx];
    ushort4 o;
    o.x = f2bf(v.x); o.y = f2bf(v.y); o.z = f2bf(v.z); o.w = f2bf(v.w);
    reinterpret_cast<ushort4*>(dst)[idx] = o;
}

// ---------------- 128x64 GEMM: C = A[M,K] @ B[N,K]^T, 3 blocks/CU at this shape ----------------
// WMODE 3: QKV merged, N=1536; region0 q (pre-scaled ESCF), region1 k, region2 vt[b][h][d][s].
template<int WMODE>
__global__ __launch_bounds__(256) void gemm128x64(const u16* __restrict__ A, const u16* __restrict__ Bm,
                                                  void* __restrict__ Cout, void* __restrict__ Cout2,
                                                  void* __restrict__ Cout3, int M, int N, int K) {
    __shared__ u16 As[128*64];
    __shared__ u16 Bs[64*64];
    const int bm0 = blockIdx.x * 128, bn0 = blockIdx.y * 64;
    const int t = threadIdx.x;
    const int w = t >> 6, l = t & 63;
    const int lg = l >> 4, lr = l & 15;
    f32x4 acc[2][4] = {};
    const int sr8 = l >> 3;
    const int swc = ((l & 7) ^ (sr8 & 7)) * 8;
    const int arow = w*32 + sr8;                 // A: wave w stages rows w*32 + g*8 + sr8
    const int brow = w*8 + sr8;                  // B: stages rows g*32 + w*8 + sr8
    const u16* asrc = A  + (size_t)(bm0 + arow)*K + swc;
    const u16* bsrc = Bm + (size_t)(bn0 + brow)*K + swc;

    for (int k0 = 0; k0 < K; k0 += 64) {
        #pragma unroll
        for (int g = 0; g < 4; g++)
            GLDS16(asrc + (size_t)g*8*K + k0, &As[w*2048 + g*512]);
        #pragma unroll
        for (int g = 0; g < 2; g++)
            GLDS16(bsrc + (size_t)g*32*K + k0, &Bs[g*2048 + w*512]);
        __syncthreads();
        #pragma unroll
        for (int ks = 0; ks < 2; ks++) {
            const int swr = ((ks*4 + lg) ^ (lr & 7)) * 8;
            s16x8 af[2], bfr[4];
            #pragma unroll
            for (int fm = 0; fm < 2; fm++)
                af[fm] = *(const s16x8*)&As[(w*32 + fm*16 + lr)*64 + swr];
            #pragma unroll
            for (int fn = 0; fn < 4; fn++)
                bfr[fn] = *(const s16x8*)&Bs[(fn*16 + lr)*64 + swr];
            #pragma unroll
            for (int fm = 0; fm < 2; fm++)
                #pragma unroll
                for (int fn = 0; fn < 4; fn++)
                    acc[fm][fn] = mfma16(af[fm], bfr[fn], acc[fm][fn]);
        }
        __syncthreads();
    }

    const int region = (WMODE == 3) ? (bn0 >> 9) : 0;
    const float qsc = (WMODE == 3 && region == 0) ? ESCF : 1.0f;
    #pragma unroll
    for (int fm = 0; fm < 2; fm++) {
        #pragma unroll
        for (int fn = 0; fn < 4; fn++) {
            const int mb = bm0 + w*32 + fm*16 + lg*4;
            const int n  = bn0 + fn*16 + lr;
            if (WMODE == 2) {
                float* C = (float*)Cout;
                #pragma unroll
                for (int i = 0; i < 4; i++)
                    C[(size_t)(mb + i)*N + n] = acc[fm][fn][i];
            } else {
                const int nl = n & 511;
                if (region == 2) {
                    const int b = mb >> 11, s0 = mb & 2047;
                    const int h = nl >> 6, d = nl & 63;
                    ushort4 pk;
                    pk.x = f2bf(acc[fm][fn][0]);
                    pk.y = f2bf(acc[fm][fn][1]);
                    pk.z = f2bf(acc[fm][fn][2]);
                    pk.w = f2bf(acc[fm][fn][3]);
                    *(ushort4*)((u16*)Cout3 + (size_t)((b*8 + h)*64 + d)*2048 + s0) = pk;
                } else {
                    u16* C = region == 0 ? (u16*)Cout : (u16*)Cout2;
                    #pragma unroll
                    for (int i = 0; i < 4; i++)
                        C[(size_t)(mb + i)*512 + nl] = f2bf(acc[fm][fn][i] * qsc);
                }
            }
        }
    }
}

// ---------------- fused: combine split-K partials + normalize + Wo GEMM (32x64 tile) ----------------
// 1024 blocks = 4 blocks/CU; grid_y = 8 keeps A-combine duplication unchanged vs 64x64.
__global__ __launch_bounds__(256) void gemm_bt2f(const u16* __restrict__ opart,
                                                 const float* __restrict__ gpart,
                                                 const u16* __restrict__ Bm,
                                                 u16* __restrict__ Cout) {
    __shared__ u16 As[32*64];
    __shared__ u16 Bs[64*64];
    __shared__ float ginv[32][9];   // +1 pad: spread banks
    const int bm0 = blockIdx.x * 32, bn0 = blockIdx.y * 64;
    const int t = threadIdx.x;
    const int w = t >> 6, l = t & 63;
    const int lg = l >> 4, lr = l & 15;
    const int wm = w >> 1, wn = w & 1;
    f32x4 acc[2] = {};
    const int srow = t >> 3;            // 0..31
    const int c8 = t & 7;
    const int scol = c8 * 8;
    const int swz = (c8 ^ (srow & 7)) * 8;   // swizzled chunk (write pos for A, src col for B)

    // precompute 1/denominator for the 32 rows x 8 heads this block touches (256 = 1/thread)
    {
        const int r = t >> 3, h = t & 7;
        const int rg = bm0 + r;
        const int b = rg >> 11, s = rg & 2047;
        float g = gpart[(size_t)(b*8 + h)*SEQ + s]
                + gpart[(size_t)(16 + b*8 + h)*SEQ + s]
                + gpart[(size_t)(32 + b*8 + h)*SEQ + s]
                + gpart[(size_t)(48 + b*8 + h)*SEQ + s];
        ginv[r][h] = frcp(g);
    }
    __syncthreads();

    for (int k0 = 0; k0 < DIMD; k0 += 64) {
        const int h = k0 >> 6;          // head of this k-slab (cols k0..k0+63)
        // B: async staged, source pre-swizzled -> linear LDS holds col p^(row&7) at pos p
        #pragma unroll
        for (int c = 0; c < 2; c++) {
            const u16* gb = Bm + (size_t)(bn0 + c*32 + srow)*DIMD + k0 + swz;
            GLDS16(gb, (char*)Bs + c*4096 + w*1024);
        }
        // A: reg-staged fused normalize of 4 partials (32 rows, 1 chunk/thread)
        {
            const int rl = srow;
            const int rg = bm0 + rl;
            const u16* oprow = opart + (size_t)rg*DIMD + k0 + scol;
            s16x8 p0 = *(const s16x8*)(oprow);
            s16x8 p1 = *(const s16x8*)(oprow + (size_t)MROWS*DIMD);
            s16x8 p2 = *(const s16x8*)(oprow + (size_t)2*MROWS*DIMD);
            s16x8 p3 = *(const s16x8*)(oprow + (size_t)3*MROWS*DIMD);
            const float inv = ginv[rl][h];
            union { u32 uu[4]; s16x8 v; } av;
            #pragma unroll
            for (int e2 = 0; e2 < 4; e2++) {
                const float s0 = (bf2f((u16)p0[2*e2]) + bf2f((u16)p1[2*e2]))
                               + (bf2f((u16)p2[2*e2]) + bf2f((u16)p3[2*e2]));
                const float s1 = (bf2f((u16)p0[2*e2+1]) + bf2f((u16)p1[2*e2+1]))
                               + (bf2f((u16)p2[2*e2+1]) + bf2f((u16)p3[2*e2+1]));
                asm("v_cvt_pk_bf16_f32 %0, %1, %2" : "=v"(av.uu[e2]) : "v"(s0*inv), "v"(s1*inv));
            }
            *(s16x8*)&As[rl*64 + swz] = av.v;
        }
        __syncthreads();
        #pragma unroll
        for (int ks = 0; ks < 2; ks++) {
            const int rc = ((ks*4 + lg) ^ (lr & 7)) * 8;
            s16x8 af = *(const s16x8*)&As[(wm*16 + lr)*64 + rc];
            s16x8 bfr[2];
            #pragma unroll
            for (int fn = 0; fn < 2; fn++)
                bfr[fn] = *(const s16x8*)&Bs[(wn*32 + fn*16 + lr)*64 + rc];
            #pragma unroll
            for (int fn = 0; fn < 2; fn++)
                acc[fn] = mfma16(af, bfr[fn], acc[fn]);
        }
        __syncthreads();
    }

    #pragma unroll
    for (int fn = 0; fn < 2; fn++) {
        const int mb = bm0 + wm*16 + lg*4;
        const int n  = bn0 + wn*32 + fn*16 + lr;
        #pragma unroll
        for (int i = 0; i < 4; i++)
            Cout[(size_t)(mb + i)*DIMD + n] = f2bf(acc[fn][i]);
    }
}

// ---------------- attention phase: 64 keys via 32x32x16 MFMA, P in-register ----------------
// Only 2 score tiles live at once (sc0, sc1) -> sc+o accumulator footprint = 64 AGPRs,
// leaving room under the 128-reg budget for 4 waves/SIMD.
__device__ __forceinline__ void attn_phase64(const u16* Kc, const u16* Vc, const s16x8* qf,
                                             f32x16& o0, f32x16& o1, float& gacc,
                                             int ln, int hi, int l7) {
    f32x16 sc0 = {}, sc1 = {};
    __builtin_amdgcn_s_setprio(1);
    #pragma unroll
    for (int c = 0; c < 4; c++) {
        const int ch = (((c << 1) | hi) ^ l7) * 8;
        s16x8 kf0 = *(const s16x8*)&Kc[ln*64 + ch];
        s16x8 kf1 = *(const s16x8*)&Kc[(32 + ln)*64 + ch];
        sc0 = mfma32(kf0, qf[c], sc0);
        sc1 = mfma32(kf1, qf[c], sc1);
    }
    __builtin_amdgcn_s_setprio(0);
    #pragma unroll
    for (int kb = 0; kb < 2; kb++) {
        const f32x16& sc = kb ? sc1 : sc0;
        u32 u[4][2];
        #pragma unroll
        for (int b2 = 0; b2 < 4; b2++) {
            float ww[4];
            #pragma unroll
            for (int r = 0; r < 4; r++) {
                const float s = sc[b2*4 + r];
                const float e = fexp2(s);
                const float hs = __builtin_amdgcn_fmed3f(s*HSC2 + 0.5f, 0.f, 1.f);
                ww[r] = e*hs;
            }
            gacc += (ww[0] + ww[1]) + (ww[2] + ww[3]);
            asm("v_cvt_pk_bf16_f32 %0, %1, %2" : "=v"(u[b2][0]) : "v"(ww[0]), "v"(ww[1]));
            asm("v_cvt_pk_bf16_f32 %0, %1, %2" : "=v"(u[b2][1]) : "v"(ww[2]), "v"(ww[3]));
        }
        #pragma unroll
        for (int c16 = 0; c16 < 2; c16++) {
            u32 x0 = u[2*c16][0], y0 = u[2*c16+1][0];
            u32 x1 = u[2*c16][1], y1 = u[2*c16+1][1];
            asm("v_permlane32_swap_b32 %0, %1" : "+v"(x0), "+v"(y0));
            asm("v_permlane32_swap_b32 %0, %1" : "+v"(x1), "+v"(y1));
            union { u32 uu[4]; s16x8 v; } pa;
            pa.uu[0] = x0; pa.uu[1] = x1; pa.uu[2] = y0; pa.uu[3] = y1;
            const int ccv = kb*4 + c16*2 + hi;
            s16x8 vf0 = *(const s16x8*)&Vc[(size_t)ln*64        + (ccv ^ l7)*8];
            s16x8 vf1 = *(const s16x8*)&Vc[(size_t)(32 + ln)*64 + (ccv ^ l7)*8];
            __builtin_amdgcn_s_setprio(1);
            o0 = mfma32(pa.v, vf0, o0);
            o1 = mfma32(pa.v, vf1, o1);
            __builtin_amdgcn_s_setprio(0);
        }
    }
}

// ---------------- fused flash attention, split-K(4), 32KB LDS, 128-reg budget ----------------
// __launch_bounds__(256, 4): pin allocator to <=128 VGPR+AGPR -> 4 waves/SIMD -> 4 blocks/CU
// -> 1024 blocks = exactly one balanced residency pass (was 3 blocks/CU, 1.33 imbalanced
// passes with the unconstrained ~148-reg footprint).
__global__ __launch_bounds__(256, 4) void attn_split(const u16* __restrict__ q, const u16* __restrict__ k,
                                                     const u16* __restrict__ vt,
                                                     u16* __restrict__ opart, float* __restrict__ gpart) {
    __shared__ u16 Ks[2][64*64];
    __shared__ u16 Vs[2][64*64];
    const int bid = blockIdx.x;
    const int xcd = bid & 7, j = bid >> 3;      // j: 0..127
    const int g8 = j >> 4, qt = j & 15;         // 8 (bh,ks) groups per XCD, 16 q-tiles each
    const int bhks = xcd*8 + g8;                // 0..63
    const int bh = bhks >> 2, ks = bhks & 3;
    const int b = bh >> 3, h = bh & 7;
    const int qb0 = qt * 128;
    const int t = threadIdx.x;
    const int w = t >> 6, l = t & 63;
    const int ln = l & 31, hi = l >> 5, l7 = l & 7;

    // Q B-fragments: wave w owns q-rows qb0 + w*32 + ln (pre-scaled by ESCF)
    const size_t qrow = (size_t)(b*SEQ + qb0 + w*32 + ln);
    s16x8 qf[4];
    #pragma unroll
    for (int c = 0; c < 4; c++)
        qf[c] = *(const s16x8*)(q + qrow*DIMD + h*HDIM + c*16 + hi*8);

    // staging: wave w stages rows w*16 + g*8 + (l>>3); row&7 == l>>3 -> same XOR chunk
    const int sr = l >> 3;
    const int swc = ((l & 7) ^ sr) * 8;
    const u16* ksrc = k  + (size_t)(b*SEQ + ks*512 + w*16 + sr)*DIMD + h*HDIM + swc;
    const u16* vsrc = vt + (size_t)bh*HDIM*SEQ + (size_t)(w*16 + sr)*SEQ + ks*512 + swc;
    const int ldsw = w*1024;

    f32x16 o0 = {}, o1 = {};
    float gacc = 0.f;

    // prologue: stage key-tile 0 (64 keys)
    #pragma unroll
    for (int g = 0; g < 2; g++) {
        GLDS16(ksrc + (size_t)g*8*DIMD, &Ks[0][ldsw + g*512]);
        GLDS16(vsrc + (size_t)g*8*SEQ,  &Vs[0][ldsw + g*512]);
    }
    __syncthreads();

    #pragma unroll 1
    for (int tp = 0; tp < 4; ++tp) {
        const int tt0 = tp*2;
        {
            const int adv = (tt0 + 1) * 64;
            #pragma unroll
            for (int g = 0; g < 2; g++) {
                GLDS16(ksrc + (size_t)(adv)*DIMD + (size_t)g*8*DIMD, &Ks[1][ldsw + g*512]);
                GLDS16(vsrc + (size_t)g*8*SEQ + adv,                 &Vs[1][ldsw + g*512]);
            }
        }
        attn_phase64(&Ks[0][0], &Vs[0][0], qf, o0, o1, gacc, ln, hi, l7);
        __syncthreads();
        if (tp < 3) {
            const int adv = (tt0 + 2) * 64;
            #pragma unroll
            for (int g = 0; g < 2; g++) {
                GLDS16(ksrc + (size_t)(adv)*DIMD + (size_t)g*8*DIMD, &Ks[0][ldsw + g*512]);
                GLDS16(vsrc + (size_t)g*8*SEQ + adv,                 &Vs[0][ldsw + g*512]);
            }
        }
        attn_phase64(&Ks[1][0], &Vs[1][0], qf, o0, o1, gacc, ln, hi, l7);
        __syncthreads();
    }

    // partial denominator (sum over this key-split), q lives in lanes l and l^32
    gacc += __shfl_xor(gacc, 32);
    if (l < 32)
        gpart[((size_t)ks*16 + bh)*SEQ + qb0 + w*32 + l] = gacc;

    // partial output (unnormalized, bf16)
    u16* op = opart + ((size_t)ks*MROWS + b*SEQ + qb0 + w*32)*DIMD + h*HDIM;
    #pragma unroll
    for (int i = 0; i < 16; i++) {
        const int qr = (i & 3) + 8*(i >> 2) + 4*hi;
        op[(size_t)qr*DIMD + ln]      = f2bf(o0[i]);
        op[(size_t)qr*DIMD + 32 + ln] = f2bf(o1[i]);
    }
}

// ---------------- softsign + softshrink residual + LayerNorm (bf16 proj in) ----------------
__global__ __launch_bounds__(256) void ln_epilogue(const u16* __restrict__ proj, const float* __restrict__ x,
                                                   const float* __restrict__ gamma, const float* __restrict__ beta,
                                                   float* __restrict__ out) {
    const int row = blockIdx.x*4 + (threadIdx.x >> 6);
    const int l = threadIdx.x & 63;
    const u16* pr = proj + (size_t)row*DIMD + l*8;
    const float* xr = x  + (size_t)row*DIMD + l*8;
    s16x8 pv = *(const s16x8*)pr;
    float tv[8];
    float s = 0.f, s2 = 0.f;
    #pragma unroll
    for (int j = 0; j < 2; j++) {
        float4 xv = *(const float4*)(xr + j*4);
        float xa[4] = {xv.x, xv.y, xv.z, xv.w};
        #pragma unroll
        for (int qq = 0; qq < 4; qq++) {
            const float p = bf2f((u16)pv[j*4+qq]);
            const float ss = p / (1.f + fabsf(p));
            const float xx = xa[qq];
            const float sh = xx > 0.5f ? xx - 0.5f : (xx < -0.5f ? xx + 0.5f : 0.f);
            const float tt = ss + sh;
            tv[j*4+qq] = tt; s += tt; s2 += tt*tt;
        }
    }
    #pragma unroll
    for (int m = 1; m < 64; m <<= 1) { s += __shfl_xor(s, m); s2 += __shfl_xor(s2, m); }
    const float mu = s * (1.f/512.f);
    float var = s2 * (1.f/512.f) - mu*mu;
    const float rstd = rsqrtf(var + 1e-5f);
    #pragma unroll
    for (int j = 0; j < 2; j++) {
        float4 g  = *(const float4*)(gamma + l*8 + j*4);
        float4 bb = *(const float4*)(beta  + l*8 + j*4);
        float4 ov;
        ov.x = (tv[j*4+0]-mu)*rstd*g.x + bb.x;
        ov.y = (tv[j*4+1]-mu)*rstd*g.y + bb.y;
        ov.z = (tv[j*4+2]-mu)*rstd*g.z + bb.z;
        ov.w = (tv[j*4+3]-mu)*rstd*g.w + bb.w;
        *(float4*)(out + (size_t)row*DIMD + l*8 + j*4) = ov;
    }
}

extern "C" void kernel_launch(void* const* d_in, const int* in_sizes, int n_in,
                              void* d_out, int out_size, void* d_ws, size_t ws_size,
                              hipStream_t stream) {
    const float* x     = (const float*)d_in[0];
    const float* Wq    = (const float*)d_in[1];
    const float* Wk    = (const float*)d_in[2];
    const float* Wv    = (const float*)d_in[3];
    const float* Wo    = (const float*)d_in[4];
    const float* gamma = (const float*)d_in[5];
    const float* beta  = (const float*)d_in[6];
    float* out = (float*)d_out;
    char* ws = (char*)d_ws;

    u16* xb    = (u16*)(ws);                               // 4 MB
    u16* wqkvb = (u16*)(ws + (4<<20));                     // 1.5 MB  [1536,512]
    u16* wob   = (u16*)(ws + (4<<20) + (1536<<10));        // 0.5 MB
    u16* qb    = (u16*)(ws + (6<<20));                     // 4 MB
    u16* kb    = (u16*)(ws + (10<<20));                    // 4 MB
    u16* vtb   = (u16*)(ws + (14<<20));                    // 4 MB
    u16* proj  = (u16*)(ws + (22<<20));                    // 4 MB (bf16)
    u16* opart = (u16*)(ws + (26<<20));                    // 16 MB [4][4096][512] bf16
    float* gpart = (float*)(ws + (42<<20));                // 512 KB [4][16][2048] f32

    cvt_all<<<3072, 256, 0, stream>>>(x, Wq, Wk, Wv, Wo, xb, wqkvb, wob);

    // 768 blocks = 3/CU
    gemm128x64<3><<<dim3(MROWS/128, 1536/64), 256, 0, stream>>>(xb, wqkvb, qb, kb, vtb, MROWS, 1536, DIMD);

    // 1024 blocks: 8 XCD x 8 (bh,ks) groups x 16 q-tiles; 4 blocks/CU under the 128-reg budget
    attn_split<<<1024, 256, 0, stream>>>(qb, kb, vtb, opart, gpart);

    // fused combine + Wo projection, 32x64 tile: 1024 blocks = 4/CU
    gemm_bt2f<<<dim3(MROWS/32, DIMD/64), 256, 0, stream>>>(opart, gpart, wob, proj);

    ln_epilogue<<<MROWS/4, 256, 0, stream>>>(proj, x, gamma, beta, out);
}